// Round 8
// baseline (1180.112 us; speedup 1.0000x reference)
//
#include <hip/hip_runtime.h>

#define NUSER 100000
#define NITEM 50000
#define NNODE 150000
#define DIM 128
#define NB 3
#define NL 2
#define BN_EPS 1e-5f
#define NT3P 450560             // 440 * 1024, padded NB*NNODE
#define SCAN_BLOCKS 440
#define TILESN 2344             // ceil(NNODE/64)  (sage tiles)
#define NT32 4688               // ceil(NNODE/32)  (attn tiles)

typedef unsigned short u16;
typedef _Float16 f16;
typedef __attribute__((ext_vector_type(8))) _Float16 f16x8;
typedef __attribute__((ext_vector_type(8))) unsigned short us8;
typedef __attribute__((ext_vector_type(4))) float f32x4;

__device__ __forceinline__ float h2f(u16 u) { f16 h; __builtin_memcpy(&h, &u, 2); return (float)h; }
__device__ __forceinline__ u16 f2h(float f) { f16 h = (f16)f; u16 u; __builtin_memcpy(&u, &h, 2); return u; }

struct Out3 { u16* p[3]; };
struct WPtrs { const float* s[8]; };
template <bool B> struct BNC { static constexpr bool value = B; };

// ---------------- CSR build ----------------

__global__ __launch_bounds__(256) void count_edges(const int* __restrict__ ei,
                                                   const int* __restrict__ et, int E,
                                                   int* __restrict__ cnt) {
    int t = blockIdx.x * 256 + threadIdx.x;
    if (t >= E) return;
    atomicAdd(&cnt[et[t] * NNODE + ei[E + t]], 1);
}

__global__ __launch_bounds__(256) void scan1(const int* __restrict__ cnt, int* __restrict__ bsum) {
    __shared__ int sh[256];
    int tid = threadIdx.x;
    int base = blockIdx.x * 1024 + tid * 4;
    int4 v = *(const int4*)(cnt + base);
    sh[tid] = v.x + v.y + v.z + v.w;
    __syncthreads();
    for (int off = 128; off > 0; off >>= 1) {
        if (tid < off) sh[tid] += sh[tid + off];
        __syncthreads();
    }
    if (tid == 0) bsum[blockIdx.x] = sh[0];
}

__global__ __launch_bounds__(512) void scan2(int* __restrict__ bsum, int nb) {
    __shared__ int sh[512];
    int tid = threadIdx.x;
    sh[tid] = (tid < nb) ? bsum[tid] : 0;
    __syncthreads();
    for (int off = 1; off < 512; off <<= 1) {
        int v = sh[tid];
        int add = (tid >= off) ? sh[tid - off] : 0;
        __syncthreads();
        sh[tid] = v + add;
        __syncthreads();
    }
    if (tid < nb) bsum[tid] = (tid == 0) ? 0 : sh[tid - 1];
}

__global__ __launch_bounds__(256) void scan3(const int* __restrict__ cnt, const int* __restrict__ bsum,
                                             int* __restrict__ row_start, int* __restrict__ cur) {
    __shared__ int sh[256];
    int tid = threadIdx.x;
    int base = blockIdx.x * 1024 + tid * 4;
    int4 v = *(const int4*)(cnt + base);
    sh[tid] = v.x + v.y + v.z + v.w;
    __syncthreads();
    for (int off = 1; off < 256; off <<= 1) {
        int a = sh[tid];
        int add = (tid >= off) ? sh[tid - off] : 0;
        __syncthreads();
        sh[tid] = a + add;
        __syncthreads();
    }
    int excl = ((tid == 0) ? 0 : sh[tid - 1]) + bsum[blockIdx.x];
    int4 o;
    o.x = excl; o.y = excl + v.x; o.z = o.y + v.y; o.w = o.z + v.z;
    *(int4*)(row_start + base) = o;
    *(int4*)(cur + base) = o;
}

__global__ __launch_bounds__(256) void scatter_csr(const int* __restrict__ ei,
                                                   const int* __restrict__ et, int E,
                                                   int* __restrict__ cur, int* __restrict__ adj) {
    int t = blockIdx.x * 256 + threadIdx.x;
    if (t >= E) return;
    int pos = atomicAdd(&cur[et[t] * NNODE + ei[E + t]], 1);
    adj[pos] = ei[t];
}

// ---------------- weight conversion: all 20 mats, transpose + fp16 ----------------
// mat order: 0 user, 1 item, 2..7 Wl, 8..13 Wr, 14 q, 15..17 key, 18 fuse, 19 ref

__global__ __launch_bounds__(256) void wconv_all(WPtrs w, u16* __restrict__ dst) {
    int gid = blockIdx.x * 256 + threadIdx.x;
    if (gid >= 20 * 16384) return;
    int m = gid >> 14, idx = gid & 16383;
    int k = idx & 127, n = idx >> 7;
    const float* src; int li;
    if (m == 0)       { src = w.s[0]; li = 0; }
    else if (m == 1)  { src = w.s[1]; li = 0; }
    else if (m < 8)   { src = w.s[2]; li = m - 2; }
    else if (m < 14)  { src = w.s[3]; li = m - 8; }
    else if (m == 14) { src = w.s[4]; li = 0; }
    else if (m < 18)  { src = w.s[5]; li = m - 15; }
    else if (m == 18) { src = w.s[6]; li = 0; }
    else              { src = w.s[7]; li = 0; }
    dst[(size_t)m * 16384 + idx] = f2h(src[(size_t)li * 16384 + k * 128 + n]);
}

// ---------------- SAGE layer, all 3 behaviors in one launch ----------------
// grid = 3*TILESN, b = blockIdx/TILESN. Computes pre-BN
//   h_out = mean_gather(act(h_in))@Wl + bl + act(h_in)@Wr, accumulating BN
// stats, where act = BN(layer0-stats)+ReLU for layer 1, identity for layer 0.
// NEW (R8): bn_apply pass is FOLDED IN — layer 1 applies BN+ReLU in f32 at
// both consumption points (gather elements + root A2), using per-block BN
// constants staged in LDS (scb/sfb). Removes the 460MB bn_apply pass.
// Gather: 8 lanes/row x 16 cols, 2 rows/thread, quad edge unroll.
// VGPR ~95 (sc/sf 32 regs) -> (256,4): 4 waves/EU, budget 128, no spill.
// Layer-1 outputs for b=1,2 go to d_out in 32-ROW TILE-BLOCK layout: attn
// tile tt owns u16 bytes [tt*16384, +16384); last tile -> ws tail buffer.

__global__ __launch_bounds__(256, 4) void sage_layer(
    const u16* __restrict__ hin0, const u16* __restrict__ wt_Wl,
    const u16* __restrict__ wt_Wr, const float* __restrict__ sage_bl,
    const float* __restrict__ gamma, const float* __restrict__ beta,
    float* __restrict__ stats6, Out3 outs, int layer,
    const int* __restrict__ adj, const int* __restrict__ row_start,
    const int* __restrict__ cnt) {
    __shared__ u16 T1[64][136];
    __shared__ float scb[DIM], sfb[DIM];
    __shared__ float sstat[256];
    const int tid = threadIdx.x;
    const int b = blockIdx.x / TILESN;
    const int tile = blockIdx.x % TILESN;
    const int r0 = tile * 64;
    const int bl = b * NL + layer;
    const u16* hin = hin0 + (layer ? (size_t)b * NNODE * DIM : 0);
    const u16* Wl = wt_Wl + (size_t)bl * 16384;
    const u16* Wr = wt_Wr + (size_t)bl * 16384;

    // BN constants for the INPUT activation (layer-0 stats), identity for L0
    if (tid < DIM) {
        float scv = 1.f, sfv = 0.f;
        if (layer) {
            const int bl0 = b * NL;
            const float* st = stats6 + bl0 * 256;
            const float invN = 1.0f / (float)NNODE;
            float mu = st[tid] * invN;
            float var = fmaxf(st[DIM + tid] * invN - mu * mu, 0.f);
            scv = gamma[bl0 * DIM + tid] * rsqrtf(var + BN_EPS);
            sfv = beta[bl0 * DIM + tid] - mu * scv;
        }
        scb[tid] = scv; sfb[tid] = sfv;
    }
    sstat[tid] = 0.f;
    __syncthreads();

    // stage T1: mean-gather, 8 lanes x 16 cols per row, 2 rows/thread,
    // quad/pair/single edge unroll; BN+ReLU inline in f32 for layer 1.
    {
        const int lrow = tid >> 3;              // 0..31
        const int c0 = (tid & 7) * 16;
        auto run = [&](auto bnc) {
            constexpr bool BN = decltype(bnc)::value;
            float scl[16], shf[16];
            if constexpr (BN) {
#pragma unroll
                for (int j = 0; j < 16; ++j) { scl[j] = scb[c0 + j]; shf[j] = sfb[c0 + j]; }
            }
            for (int half = 0; half < 2; ++half) {
                const int row = lrow + half * 32;
                float a[16];
#pragma unroll
                for (int j = 0; j < 16; ++j) a[j] = 0.f;
                const int n = r0 + row;
                if (n < NNODE) {
                    const int base = b * NNODE + n;
                    const int s0 = row_start[base];
                    const int deg = cnt[base];
                    auto accU = [&](us8 u0, us8 u1) {
#pragma unroll
                        for (int j = 0; j < 8; ++j) {
                            float y0 = h2f(u0[j]), y1 = h2f(u1[j]);
                            if constexpr (BN) {
                                y0 = fmaxf(y0 * scl[j] + shf[j], 0.f);
                                y1 = fmaxf(y1 * scl[8 + j] + shf[8 + j], 0.f);
                            }
                            a[j] += y0; a[8 + j] += y1;
                        }
                    };
                    int e = 0;
                    for (; e + 3 < deg; e += 4) {
                        const int i0 = adj[s0 + e],     i1 = adj[s0 + e + 1];
                        const int i2 = adj[s0 + e + 2], i3 = adj[s0 + e + 3];
                        const u16* p0 = hin + (size_t)i0 * DIM + c0;
                        const u16* p1 = hin + (size_t)i1 * DIM + c0;
                        const u16* p2 = hin + (size_t)i2 * DIM + c0;
                        const u16* p3 = hin + (size_t)i3 * DIM + c0;
                        us8 u00 = *(const us8*)p0, u01 = *(const us8*)(p0 + 8);
                        us8 u10 = *(const us8*)p1, u11 = *(const us8*)(p1 + 8);
                        us8 u20 = *(const us8*)p2, u21 = *(const us8*)(p2 + 8);
                        us8 u30 = *(const us8*)p3, u31 = *(const us8*)(p3 + 8);
                        accU(u00, u01); accU(u10, u11); accU(u20, u21); accU(u30, u31);
                    }
                    if (e + 1 < deg) {
                        const u16* p0 = hin + (size_t)adj[s0 + e] * DIM + c0;
                        const u16* p1 = hin + (size_t)adj[s0 + e + 1] * DIM + c0;
                        us8 u00 = *(const us8*)p0, u01 = *(const us8*)(p0 + 8);
                        us8 u10 = *(const us8*)p1, u11 = *(const us8*)(p1 + 8);
                        accU(u00, u01); accU(u10, u11);
                        e += 2;
                    }
                    if (e < deg) {
                        const u16* p0 = hin + (size_t)adj[s0 + e] * DIM + c0;
                        us8 u00 = *(const us8*)p0, u01 = *(const us8*)(p0 + 8);
                        accU(u00, u01);
                    }
                    const float s = 1.0f / (float)(deg > 1 ? deg : 1);
#pragma unroll
                    for (int j = 0; j < 16; ++j) a[j] *= s;
                }
                us8 o0, o1;
#pragma unroll
                for (int j = 0; j < 8; ++j) { o0[j] = f2h(a[j]); o1[j] = f2h(a[8 + j]); }
                *(us8*)&T1[row][c0] = o0;
                *(us8*)&T1[row][c0 + 8] = o1;
            }
        };
        if (layer) run(BNC<true>{});
        else       run(BNC<false>{});
    }
    __syncthreads();

    // dual MFMA GEMM: A1 from LDS, A2 direct from global (BN+ReLU inline for L1)
    const int wave = tid >> 6, lane = tid & 63, q = lane >> 4, rlo = lane & 15;
    const f16x8 zf = (f16x8)(f16)0.f;
    f32x4 acc[4][2];
#pragma unroll
    for (int t = 0; t < 4; ++t) { acc[t][0] = (f32x4)0.f; acc[t][1] = (f32x4)0.f; }
#pragma unroll
    for (int kc = 0; kc < DIM; kc += 32) {
        f16x8 b1v[2], b2v[2];
#pragma unroll
        for (int c = 0; c < 2; ++c) {
            b1v[c] = *(const f16x8*)(Wl + (size_t)(wave * 32 + 16 * c + rlo) * DIM + kc + q * 8);
            b2v[c] = *(const f16x8*)(Wr + (size_t)(wave * 32 + 16 * c + rlo) * DIM + kc + q * 8);
        }
        float scA[8], sfA[8];
        if (layer) {
#pragma unroll
            for (int j = 0; j < 8; ++j) {
                scA[j] = scb[kc + q * 8 + j];
                sfA[j] = sfb[kc + q * 8 + j];
            }
        }
#pragma unroll
        for (int t = 0; t < 4; ++t) {
            f16x8 a1 = *(const f16x8*)&T1[16 * t + rlo][kc + q * 8];
            int rr = r0 + 16 * t + rlo;
            f16x8 a2;
            if (rr < NNODE) {
                us8 u = *(const us8*)(hin + (size_t)rr * DIM + kc + q * 8);
                if (layer) {
                    f16x8 tmp;
#pragma unroll
                    for (int j = 0; j < 8; ++j)
                        tmp[j] = (f16)fmaxf(h2f(u[j]) * scA[j] + sfA[j], 0.f);
                    a2 = tmp;
                } else {
                    __builtin_memcpy(&a2, &u, 16);
                }
            } else {
                a2 = zf;
            }
            acc[t][0] = __builtin_amdgcn_mfma_f32_16x16x32_f16(a1, b1v[0], acc[t][0], 0, 0, 0);
            acc[t][1] = __builtin_amdgcn_mfma_f32_16x16x32_f16(a1, b1v[1], acc[t][1], 0, 0, 0);
            acc[t][0] = __builtin_amdgcn_mfma_f32_16x16x32_f16(a2, b2v[0], acc[t][0], 0, 0, 0);
            acc[t][1] = __builtin_amdgcn_mfma_f32_16x16x32_f16(a2, b2v[1], acc[t][1], 0, 0, 0);
        }
    }

    const int col0 = wave * 32 + rlo, col1 = col0 + 16;
    const float bb0 = sage_bl[bl * DIM + col0], bb1 = sage_bl[bl * DIM + col1];
    const bool tiled = (layer == 1) && (b > 0);
    float rs0 = 0, rq0 = 0, rs1 = 0, rq1 = 0;
#pragma unroll
    for (int t = 0; t < 4; ++t) {
#pragma unroll
        for (int r = 0; r < 4; ++r) {
            int rloc = 16 * t + q * 4 + r;
            int row = r0 + rloc;
            if (row >= NNODE) continue;
            float v0 = acc[t][0][r] + bb0;
            float v1 = acc[t][1][r] + bb1;
            rs0 += v0; rq0 += v0 * v0; rs1 += v1; rq1 += v1 * v1;
            if (!tiled) {
                u16* C = outs.p[b];
                C[(size_t)row * DIM + col0] = f2h(v0);
                C[(size_t)row * DIM + col1] = f2h(v1);
            } else {
                int tt = row >> 5, rl = row & 31;
                u16* base = (tt == NT32 - 1) ? outs.p[2]
                                             : outs.p[1] + (size_t)tt * 8192;
                base += (size_t)(b - 1) * 4096 + rl * DIM;
                base[col0] = f2h(v0);
                base[col1] = f2h(v1);
            }
        }
    }
    rs0 += __shfl_xor(rs0, 16); rs0 += __shfl_xor(rs0, 32);
    rq0 += __shfl_xor(rq0, 16); rq0 += __shfl_xor(rq0, 32);
    rs1 += __shfl_xor(rs1, 16); rs1 += __shfl_xor(rs1, 32);
    rq1 += __shfl_xor(rq1, 16); rq1 += __shfl_xor(rq1, 32);
    if (q == 0) {
        atomicAdd(&sstat[col0], rs0);
        atomicAdd(&sstat[DIM + col0], rq0);
        atomicAdd(&sstat[col1], rs1);
        atomicAdd(&sstat[DIM + col1], rq1);
    }
    __syncthreads();
    if (tid < DIM) {
        float* so = stats6 + bl * 256;
        atomicAdd(&so[tid], sstat[tid]);
        atomicAdd(&so[DIM + tid], sstat[DIM + tid]);
    }
}

// ---------------- fused epilogue: BN+residual, Q/K logits, softmax, fuse, refine ----------------
// One block per 32-row tile (LDS ~30KB -> 5 blocks/CU). Reads h_pre (b0 linear
// from fbuf; b1,2 from its own 16KB tile block in d_out / tail) + xh; writes
// the final f32 output over exactly that byte range.

__global__ __launch_bounds__(256) void attn_fuse(
    const u16* __restrict__ hpre0, const u16* __restrict__ hpre12,
    const u16* __restrict__ tailb, const float* __restrict__ stats6,
    const float* __restrict__ gamma, const float* __restrict__ beta,
    const u16* __restrict__ xh, const u16* __restrict__ wt,
    const float* __restrict__ query_b, const float* __restrict__ key_b,
    const float* __restrict__ fuse_b, const float* __restrict__ refine_b,
    float* __restrict__ out) {
    __shared__ __attribute__((aligned(16))) u16 St[3][32][136];
    __shared__ float sc[3][DIM], sf[3][DIM];
    __shared__ float slog[32][4];
    __shared__ float swt[32][4];
    const int tid = threadIdx.x;
    const int tile = blockIdx.x;
    const int r0 = tile * 32;
    const u16* wt_q    = wt + 14 * 16384;
    const u16* wt_key  = wt + 15 * 16384;
    const u16* wt_fuse = wt + 18 * 16384;
    const u16* wt_ref  = wt + 19 * 16384;

    if (tid < DIM) {
        const float invN = 1.0f / (float)NNODE;
#pragma unroll
        for (int b = 0; b < NB; ++b) {
            const int bl = b * NL + 1;
            const float* st = stats6 + bl * 256;
            float mu = st[tid] * invN;
            float var = fmaxf(st[DIM + tid] * invN - mu * mu, 0.f);
            float c = gamma[bl * DIM + tid] * rsqrtf(var + BN_EPS);
            sc[b][tid] = c;
            sf[b][tid] = beta[bl * DIM + tid] - mu * c;
        }
    }
    if (tid < 32) { slog[tid][0] = 0.f; slog[tid][1] = 0.f; slog[tid][2] = 0.f; }
    __syncthreads();

    // stage stack tiles: St[b] = bn(h_pre) + xh
    for (int i = tid; i < 512; i += 256) {
        int r = i >> 4, c8 = (i & 15) * 8;
        int n = r0 + r;
        if (n < NNODE) {
            us8 xv = *(const us8*)(xh + (size_t)n * DIM + c8);
#pragma unroll
            for (int b = 0; b < NB; ++b) {
                const u16* src = (b == 0)
                    ? hpre0 + (size_t)n * DIM + c8
                    : ((tile == NT32 - 1) ? tailb : hpre12 + (size_t)tile * 8192)
                      + (size_t)(b - 1) * 4096 + r * DIM + c8;
                us8 hv = __builtin_nontemporal_load((const us8*)src);
                us8 o;
#pragma unroll
                for (int j = 0; j < 8; ++j)
                    o[j] = f2h(h2f(hv[j]) * sc[b][c8 + j] + sf[b][c8 + j] + h2f(xv[j]));
                *(us8*)&St[b][r][c8] = o;
            }
        } else {
            us8 z = (us8)(u16)0;
#pragma unroll
            for (int b = 0; b < NB; ++b) *(us8*)&St[b][r][c8] = z;
        }
    }
    __syncthreads();

    const int wave = tid >> 6, lane = tid & 63, q = lane >> 4, rlo = lane & 15;
    const int col0 = wave * 32 + rlo, col1 = col0 + 16;
    const f16x8 zf = (f16x8)(f16)0.f;

    // Q GEMM: A = xh (global), B = wt_q
    f32x4 qa[2][2];
#pragma unroll
    for (int t = 0; t < 2; ++t) { qa[t][0] = (f32x4)0.f; qa[t][1] = (f32x4)0.f; }
#pragma unroll
    for (int kc = 0; kc < DIM; kc += 32) {
        f16x8 bv0 = *(const f16x8*)(wt_q + (size_t)(wave * 32 + rlo) * DIM + kc + q * 8);
        f16x8 bv1 = *(const f16x8*)(wt_q + (size_t)(wave * 32 + 16 + rlo) * DIM + kc + q * 8);
#pragma unroll
        for (int t = 0; t < 2; ++t) {
            int rr = r0 + 16 * t + rlo;
            f16x8 av = (rr < NNODE) ? *(const f16x8*)(xh + (size_t)rr * DIM + kc + q * 8) : zf;
            qa[t][0] = __builtin_amdgcn_mfma_f32_16x16x32_f16(av, bv0, qa[t][0], 0, 0, 0);
            qa[t][1] = __builtin_amdgcn_mfma_f32_16x16x32_f16(av, bv1, qa[t][1], 0, 0, 0);
        }
    }
    {
        const float qb0 = query_b[col0], qb1 = query_b[col1];
#pragma unroll
        for (int t = 0; t < 2; ++t)
#pragma unroll
            for (int r = 0; r < 4; ++r) { qa[t][0][r] += qb0; qa[t][1][r] += qb1; }
    }

    // K GEMMs + logits into LDS
#pragma unroll
    for (int b = 0; b < NB; ++b) {
        f32x4 ka[2][2];
#pragma unroll
        for (int t = 0; t < 2; ++t) { ka[t][0] = (f32x4)0.f; ka[t][1] = (f32x4)0.f; }
        const u16* Wk = wt_key + (size_t)b * 16384;
#pragma unroll
        for (int kc = 0; kc < DIM; kc += 32) {
            f16x8 bv0 = *(const f16x8*)(Wk + (size_t)(wave * 32 + rlo) * DIM + kc + q * 8);
            f16x8 bv1 = *(const f16x8*)(Wk + (size_t)(wave * 32 + 16 + rlo) * DIM + kc + q * 8);
#pragma unroll
            for (int t = 0; t < 2; ++t) {
                f16x8 av = *(const f16x8*)&St[b][16 * t + rlo][kc + q * 8];
                ka[t][0] = __builtin_amdgcn_mfma_f32_16x16x32_f16(av, bv0, ka[t][0], 0, 0, 0);
                ka[t][1] = __builtin_amdgcn_mfma_f32_16x16x32_f16(av, bv1, ka[t][1], 0, 0, 0);
            }
        }
        const float kb0 = key_b[b * DIM + col0], kb1 = key_b[b * DIM + col1];
#pragma unroll
        for (int t = 0; t < 2; ++t) {
#pragma unroll
            for (int r = 0; r < 4; ++r) {
                int rloc = 16 * t + q * 4 + r;
                float v = (ka[t][0][r] + kb0) * qa[t][0][r]
                        + (ka[t][1][r] + kb1) * qa[t][1][r];
                v += __shfl_xor(v, 1);
                v += __shfl_xor(v, 2);
                v += __shfl_xor(v, 4);
                v += __shfl_xor(v, 8);
                if (rlo == 0) atomicAdd(&slog[rloc][b], v);
            }
        }
    }
    __syncthreads();

    if (tid < 32) {
        float l0 = slog[tid][0], l1 = slog[tid][1], l2 = slog[tid][2];
        float mm = fmaxf(l0, fmaxf(l1, l2));
        float e0 = expf(l0 - mm), e1 = expf(l1 - mm), e2 = expf(l2 - mm);
        float inv = 1.0f / (e0 + e1 + e2);
        swt[tid][0] = e0 * inv; swt[tid][1] = e1 * inv; swt[tid][2] = e2 * inv;
    }
    __syncthreads();

    // fuse GEMM: facc = sum_b w_b * (St_b @ Wf)
    f32x4 facc[2][2];
#pragma unroll
    for (int t = 0; t < 2; ++t) { facc[t][0] = (f32x4)0.f; facc[t][1] = (f32x4)0.f; }
#pragma unroll
    for (int b = 0; b < NB; ++b) {
        f32x4 ga[2][2];
#pragma unroll
        for (int t = 0; t < 2; ++t) { ga[t][0] = (f32x4)0.f; ga[t][1] = (f32x4)0.f; }
#pragma unroll
        for (int kc = 0; kc < DIM; kc += 32) {
            f16x8 bv0 = *(const f16x8*)(wt_fuse + (size_t)(wave * 32 + rlo) * DIM + kc + q * 8);
            f16x8 bv1 = *(const f16x8*)(wt_fuse + (size_t)(wave * 32 + 16 + rlo) * DIM + kc + q * 8);
#pragma unroll
            for (int t = 0; t < 2; ++t) {
                f16x8 av = *(const f16x8*)&St[b][16 * t + rlo][kc + q * 8];
                ga[t][0] = __builtin_amdgcn_mfma_f32_16x16x32_f16(av, bv0, ga[t][0], 0, 0, 0);
                ga[t][1] = __builtin_amdgcn_mfma_f32_16x16x32_f16(av, bv1, ga[t][1], 0, 0, 0);
            }
        }
#pragma unroll
        for (int t = 0; t < 2; ++t) {
#pragma unroll
            for (int r = 0; r < 4; ++r) {
                int rloc = 16 * t + q * 4 + r;
                float wgt = swt[rloc][b];
                facc[t][0][r] += wgt * ga[t][0][r];
                facc[t][1][r] += wgt * ga[t][1][r];
            }
        }
    }
    __syncthreads();   // all St reads done before Rt overwrite

    // round fused to f16 into St[0] (Rt) for the refine GEMM
    {
        const float fb0 = fuse_b[col0], fb1 = fuse_b[col1];
#pragma unroll
        for (int t = 0; t < 2; ++t) {
#pragma unroll
            for (int r = 0; r < 4; ++r) {
                int rloc = 16 * t + q * 4 + r;
                St[0][rloc][col0] = f2h(facc[t][0][r] + fb0);
                St[0][rloc][col1] = f2h(facc[t][1][r] + fb1);
            }
        }
    }
    __syncthreads();

    // refine GEMM + ReLU -> f32 out (overwrites this tile's d_out block)
    f32x4 racc[2][2];
#pragma unroll
    for (int t = 0; t < 2; ++t) { racc[t][0] = (f32x4)0.f; racc[t][1] = (f32x4)0.f; }
#pragma unroll
    for (int kc = 0; kc < DIM; kc += 32) {
        f16x8 bv0 = *(const f16x8*)(wt_ref + (size_t)(wave * 32 + rlo) * DIM + kc + q * 8);
        f16x8 bv1 = *(const f16x8*)(wt_ref + (size_t)(wave * 32 + 16 + rlo) * DIM + kc + q * 8);
#pragma unroll
        for (int t = 0; t < 2; ++t) {
            f16x8 av = *(const f16x8*)&St[0][16 * t + rlo][kc + q * 8];
            racc[t][0] = __builtin_amdgcn_mfma_f32_16x16x32_f16(av, bv0, racc[t][0], 0, 0, 0);
            racc[t][1] = __builtin_amdgcn_mfma_f32_16x16x32_f16(av, bv1, racc[t][1], 0, 0, 0);
        }
    }
    {
        const float rb0 = refine_b[col0], rb1 = refine_b[col1];
#pragma unroll
        for (int t = 0; t < 2; ++t) {
#pragma unroll
            for (int r = 0; r < 4; ++r) {
                int row = r0 + 16 * t + q * 4 + r;
                if (row >= NNODE) continue;
                __builtin_nontemporal_store(fmaxf(racc[t][0][r] + rb0, 0.f),
                                            &out[(size_t)row * DIM + col0]);
                __builtin_nontemporal_store(fmaxf(racc[t][1][r] + rb1, 0.f),
                                            &out[(size_t)row * DIM + col1]);
            }
        }
    }
}

// ---------------- plain MFMA GEMM (fp16 weights), 64x128 tile ----------------
// flags: 1=relu, 8=A f32, 32=C f16 (else f32)

__global__ __launch_bounds__(256) void gemm_p(
    const void* __restrict__ Av, const u16* __restrict__ Wt,
    const float* __restrict__ bias, void* __restrict__ Cv, int M, int flags) {
    const u16* A16 = (const u16*)Av;
    const float* A32 = (const float*)Av;
    const float* bs = bias;
    const int r0 = blockIdx.x * 64;
    const int tid = threadIdx.x;
    const int wave = tid >> 6, lane = tid & 63, q = lane >> 4, rlo = lane & 15;
    f32x4 acc[4][2];
#pragma unroll
    for (int t = 0; t < 4; ++t) { acc[t][0] = (f32x4)0.f; acc[t][1] = (f32x4)0.f; }
    const f16x8 zf = (f16x8)(f16)0.f;
#pragma unroll
    for (int kc = 0; kc < DIM; kc += 32) {
        f16x8 av[4], bv[2];
#pragma unroll
        for (int t = 0; t < 4; ++t) {
            int row = r0 + 16 * t + rlo;
            if (row < M) {
                if (flags & 8) {
                    const float* p = A32 + (size_t)row * DIM + kc + q * 8;
                    f32x4 x0 = __builtin_nontemporal_load((const f32x4*)p);
                    f32x4 x1 = __builtin_nontemporal_load((const f32x4*)(p + 4));
                    f16x8 tmp;
                    tmp[0] = (f16)x0[0]; tmp[1] = (f16)x0[1]; tmp[2] = (f16)x0[2]; tmp[3] = (f16)x0[3];
                    tmp[4] = (f16)x1[0]; tmp[5] = (f16)x1[1]; tmp[6] = (f16)x1[2]; tmp[7] = (f16)x1[3];
                    av[t] = tmp;
                } else {
                    av[t] = *(const f16x8*)(A16 + (size_t)row * DIM + kc + q * 8);
                }
            } else {
                av[t] = zf;
            }
        }
#pragma unroll
        for (int c = 0; c < 2; ++c)
            bv[c] = *(const f16x8*)(Wt + (size_t)(wave * 32 + 16 * c + rlo) * DIM + kc + q * 8);
#pragma unroll
        for (int t = 0; t < 4; ++t) {
            acc[t][0] = __builtin_amdgcn_mfma_f32_16x16x32_f16(av[t], bv[0], acc[t][0], 0, 0, 0);
            acc[t][1] = __builtin_amdgcn_mfma_f32_16x16x32_f16(av[t], bv[1], acc[t][1], 0, 0, 0);
        }
    }

    const int col0 = wave * 32 + rlo, col1 = col0 + 16;
    const float bb0 = bs[col0], bb1 = bs[col1];
#pragma unroll
    for (int t = 0; t < 4; ++t) {
#pragma unroll
        for (int r = 0; r < 4; ++r) {
            int row = r0 + 16 * t + q * 4 + r;
            if (row >= M) continue;
            float v0 = acc[t][0][r] + bb0;
            float v1 = acc[t][1][r] + bb1;
            if (flags & 1) { v0 = fmaxf(v0, 0.f); v1 = fmaxf(v1, 0.f); }
            if (flags & 32) {
                ((u16*)Cv)[(size_t)row * DIM + col0] = f2h(v0);
                ((u16*)Cv)[(size_t)row * DIM + col1] = f2h(v1);
            } else {
                ((float*)Cv)[(size_t)row * DIM + col0] = v0;
                ((float*)Cv)[(size_t)row * DIM + col1] = v1;
            }
        }
    }
}

// ---------------- launch ----------------

extern "C" void kernel_launch(void* const* d_in, const int* in_sizes, int n_in,
                              void* d_out, int out_size, void* d_ws, size_t ws_size,
                              hipStream_t stream) {
    const int* edge_index    = (const int*)d_in[0];
    const int* edge_type     = (const int*)d_in[1];
    const float* item_feats  = (const float*)d_in[2];
    const float* user_emb    = (const float*)d_in[3];
    const float* user_proj_b = (const float*)d_in[5];
    const float* item_proj_b = (const float*)d_in[7];
    const float* sage_bl  = (const float*)d_in[9];
    const float* bn_gamma = (const float*)d_in[11];
    const float* bn_beta  = (const float*)d_in[12];
    const float* query_b  = (const float*)d_in[14];
    const float* key_b    = (const float*)d_in[16];
    const float* fuse_b   = (const float*)d_in[18];
    const float* refine_b = (const float*)d_in[20];
    const int E = in_sizes[1];

    const size_t ND = (size_t)NNODE * DIM;
    char* w = (char*)d_ws;
    u16* xh = (u16*)w;          w += ND * 2;              // initial x, fp16
    u16* stackb = (u16*)w;      w += NB * ND * 2;         // RAW pre-BN l0 h (BN folded into L1)
    u16* fbuf = (u16*)w;        w += ND * 2;              // h_pre layer1 slice 0
    int* cnt = (int*)w;         w += (size_t)NT3P * 4;
    int* row_start = (int*)w;   w += (size_t)NT3P * 4;
    int* cur = (int*)w;         w += (size_t)NT3P * 4;
    int* adj = (int*)w;         w += (size_t)E * 4;
    u16* wt = (u16*)w;          w += (size_t)20 * 16384 * 2;
    int* bsum = (int*)w;        w += 2048;
    float* stats6 = (float*)w;  w += 6 * 256 * 4;
    u16* tailb = (u16*)w;       w += 16384;               // last-tile h_pre slices 1,2

    const u16* wt_user = wt;
    const u16* wt_item = wt + 16384;
    const u16* wt_Wl   = wt + 2 * 16384;
    const u16* wt_Wr   = wt + 8 * 16384;

    u16* dout16 = (u16*)d_out;   // during SAGE L1: 32-row tiled h_pre slices 1,2; then final f32 out

    // ---- CSR build + weight conversion ----
    hipMemsetAsync(cnt, 0, (size_t)NT3P * 4, stream);
    hipMemsetAsync(stats6, 0, 6 * 256 * 4, stream);
    int gE = (E + 255) / 256;
    count_edges<<<gE, 256, 0, stream>>>(edge_index, edge_type, E, cnt);
    scan1<<<SCAN_BLOCKS, 256, 0, stream>>>(cnt, bsum);
    scan2<<<1, 512, 0, stream>>>(bsum, SCAN_BLOCKS);
    scan3<<<SCAN_BLOCKS, 256, 0, stream>>>(cnt, bsum, row_start, cur);
    scatter_csr<<<gE, 256, 0, stream>>>(edge_index, edge_type, E, cur, adj);

    WPtrs wp;
    wp.s[0] = (const float*)d_in[4];
    wp.s[1] = (const float*)d_in[6];
    wp.s[2] = (const float*)d_in[8];
    wp.s[3] = (const float*)d_in[10];
    wp.s[4] = (const float*)d_in[13];
    wp.s[5] = (const float*)d_in[15];
    wp.s[6] = (const float*)d_in[17];
    wp.s[7] = (const float*)d_in[19];
    wconv_all<<<1280, 256, 0, stream>>>(wp, wt);

    // ---- initial projection (f32 in, fp16 out) ----
    const int TU = (NUSER + 63) / 64, TI = (NITEM + 63) / 64;
    gemm_p<<<TU, 256, 0, stream>>>(user_emb, wt_user, user_proj_b, xh, NUSER, 8 | 32);
    gemm_p<<<TI, 256, 0, stream>>>(item_feats, wt_item, item_proj_b,
                                   xh + (size_t)NUSER * DIM, NITEM, 8 | 32);

    // ---- SAGE: layer0 (raw) -> layer1 (BN+ReLU folded into consumption) ----
    Out3 out_l0, out_l1;
    for (int b = 0; b < NB; ++b) out_l0.p[b] = stackb + (size_t)b * ND;
    out_l1.p[0] = fbuf;
    out_l1.p[1] = dout16;   // 32-row tiled layout
    out_l1.p[2] = tailb;    // last 32-row tile

    sage_layer<<<NB * TILESN, 256, 0, stream>>>(xh, wt_Wl, wt_Wr, sage_bl,
                                                bn_gamma, bn_beta,
                                                stats6, out_l0, 0,
                                                adj, row_start, cnt);
    sage_layer<<<NB * TILESN, 256, 0, stream>>>(stackb, wt_Wl, wt_Wr, sage_bl,
                                                bn_gamma, bn_beta,
                                                stats6, out_l1, 1,
                                                adj, row_start, cnt);

    // ---- fused attention epilogue: BN+residual, logits, softmax, fuse, refine ----
    attn_fuse<<<NT32, 256, 0, stream>>>(fbuf, dout16, tailb, stats6,
                                        bn_gamma, bn_beta, xh, wt,
                                        query_b, key_b, fuse_b, refine_b,
                                        (float*)d_out);
}

// Round 9
// 1014.073 us; speedup vs baseline: 1.1637x; 1.1637x over previous
//
#include <hip/hip_runtime.h>

#define NUSER 100000
#define NITEM 50000
#define NNODE 150000
#define DIM 128
#define NB 3
#define NL 2
#define BN_EPS 1e-5f
#define NT3P 450560             // 440 * 1024, padded NB*NNODE
#define SCAN_BLOCKS 440
#define TILESN 2344             // ceil(NNODE/64)  (sage tiles)
#define NT32 4688               // ceil(NNODE/32)  (attn tiles)
#define BNBLKS 720              // bn_apply blocks per behavior (grid-stride)

typedef unsigned short u16;
typedef _Float16 f16;
typedef __attribute__((ext_vector_type(8))) _Float16 f16x8;
typedef __attribute__((ext_vector_type(8))) unsigned short us8;
typedef __attribute__((ext_vector_type(4))) float f32x4;

__device__ __forceinline__ float h2f(u16 u) { f16 h; __builtin_memcpy(&h, &u, 2); return (float)h; }
__device__ __forceinline__ u16 f2h(float f) { f16 h = (f16)f; u16 u; __builtin_memcpy(&u, &h, 2); return u; }

struct Out3 { u16* p[3]; };
struct WPtrs { const float* s[8]; };

// ---------------- CSR build ----------------

__global__ __launch_bounds__(256) void count_edges(const int* __restrict__ ei,
                                                   const int* __restrict__ et, int E,
                                                   int* __restrict__ cnt) {
    int t = blockIdx.x * 256 + threadIdx.x;
    if (t >= E) return;
    atomicAdd(&cnt[et[t] * NNODE + ei[E + t]], 1);
}

__global__ __launch_bounds__(256) void scan1(const int* __restrict__ cnt, int* __restrict__ bsum) {
    __shared__ int sh[256];
    int tid = threadIdx.x;
    int base = blockIdx.x * 1024 + tid * 4;
    int4 v = *(const int4*)(cnt + base);
    sh[tid] = v.x + v.y + v.z + v.w;
    __syncthreads();
    for (int off = 128; off > 0; off >>= 1) {
        if (tid < off) sh[tid] += sh[tid + off];
        __syncthreads();
    }
    if (tid == 0) bsum[blockIdx.x] = sh[0];
}

__global__ __launch_bounds__(512) void scan2(int* __restrict__ bsum, int nb) {
    __shared__ int sh[512];
    int tid = threadIdx.x;
    sh[tid] = (tid < nb) ? bsum[tid] : 0;
    __syncthreads();
    for (int off = 1; off < 512; off <<= 1) {
        int v = sh[tid];
        int add = (tid >= off) ? sh[tid - off] : 0;
        __syncthreads();
        sh[tid] = v + add;
        __syncthreads();
    }
    if (tid < nb) bsum[tid] = (tid == 0) ? 0 : sh[tid - 1];
}

__global__ __launch_bounds__(256) void scan3(const int* __restrict__ cnt, const int* __restrict__ bsum,
                                             int* __restrict__ row_start, int* __restrict__ cur) {
    __shared__ int sh[256];
    int tid = threadIdx.x;
    int base = blockIdx.x * 1024 + tid * 4;
    int4 v = *(const int4*)(cnt + base);
    sh[tid] = v.x + v.y + v.z + v.w;
    __syncthreads();
    for (int off = 1; off < 256; off <<= 1) {
        int a = sh[tid];
        int add = (tid >= off) ? sh[tid - off] : 0;
        __syncthreads();
        sh[tid] = a + add;
        __syncthreads();
    }
    int excl = ((tid == 0) ? 0 : sh[tid - 1]) + bsum[blockIdx.x];
    int4 o;
    o.x = excl; o.y = excl + v.x; o.z = o.y + v.y; o.w = o.z + v.z;
    *(int4*)(row_start + base) = o;
    *(int4*)(cur + base) = o;
}

__global__ __launch_bounds__(256) void scatter_csr(const int* __restrict__ ei,
                                                   const int* __restrict__ et, int E,
                                                   int* __restrict__ cur, int* __restrict__ adj) {
    int t = blockIdx.x * 256 + threadIdx.x;
    if (t >= E) return;
    int pos = atomicAdd(&cur[et[t] * NNODE + ei[E + t]], 1);
    adj[pos] = ei[t];
}

// ---------------- weight conversion: all 20 mats, transpose + fp16 ----------------
// mat order: 0 user, 1 item, 2..7 Wl, 8..13 Wr, 14 q, 15..17 key, 18 fuse, 19 ref

__global__ __launch_bounds__(256) void wconv_all(WPtrs w, u16* __restrict__ dst) {
    int gid = blockIdx.x * 256 + threadIdx.x;
    if (gid >= 20 * 16384) return;
    int m = gid >> 14, idx = gid & 16383;
    int k = idx & 127, n = idx >> 7;
    const float* src; int li;
    if (m == 0)       { src = w.s[0]; li = 0; }
    else if (m == 1)  { src = w.s[1]; li = 0; }
    else if (m < 8)   { src = w.s[2]; li = m - 2; }
    else if (m < 14)  { src = w.s[3]; li = m - 8; }
    else if (m == 14) { src = w.s[4]; li = 0; }
    else if (m < 18)  { src = w.s[5]; li = m - 15; }
    else if (m == 18) { src = w.s[6]; li = 0; }
    else              { src = w.s[7]; li = 0; }
    dst[(size_t)m * 16384 + idx] = f2h(src[(size_t)li * 16384 + k * 128 + n]);
}

// ---------------- BN+ReLU apply, in place (layer-1 input activation) ----------------
// Grid-strided streaming rewrite: 720 blocks/behavior x 256 threads; stride
// 184320 us8-units is ==0 mod 16, so each thread's column phase (c8) is
// INVARIANT -> BN constants live in 16 registers loaded once, no per-element
// LDS traffic. ~13 x 16B coalesced RMW iterations per thread, ~40 VGPR,
// full occupancy. (Old version: 28k blocks, 1 elem each, ~2 TB/s, ~230us.)

__global__ __launch_bounds__(256) void bn_apply(u16* __restrict__ h,
                                                const float* __restrict__ stats6,
                                                const float* __restrict__ gamma,
                                                const float* __restrict__ beta) {
    __shared__ float sc[DIM];
    __shared__ float sf[DIM];
    const int tid = threadIdx.x;
    const int b = blockIdx.x / BNBLKS;
    const int blk = blockIdx.x % BNBLKS;
    const int bl = b * NL;   // layer-0 stats
    if (tid < DIM) {
        const float* st = stats6 + bl * 256;
        const float invN = 1.0f / (float)NNODE;
        float mu = st[tid] * invN;
        float var = fmaxf(st[DIM + tid] * invN - mu * mu, 0.f);
        float scv = gamma[bl * DIM + tid] * rsqrtf(var + BN_EPS);
        sc[tid] = scv;
        sf[tid] = beta[bl * DIM + tid] - mu * scv;
    }
    __syncthreads();
    const int UNITS = NNODE * DIM / 8;          // 2,400,000 us8 units / behavior
    const int STRIDE = BNBLKS * 256;            // 184,320 (== 0 mod 16)
    u16* hb = h + (size_t)b * NNODE * DIM;
    const int i0 = blk * 256 + tid;
    const int c8 = (i0 & 15) * 8;               // invariant across iterations
    float scl[8], sfl[8];
#pragma unroll
    for (int j = 0; j < 8; ++j) { scl[j] = sc[c8 + j]; sfl[j] = sf[c8 + j]; }
    for (int i = i0; i < UNITS; i += STRIDE) {
        u16* p = hb + (size_t)i * 8;
        us8 u = *(const us8*)p;
        us8 o;
#pragma unroll
        for (int j = 0; j < 8; ++j)
            o[j] = f2h(fmaxf(h2f(u[j]) * scl[j] + sfl[j], 0.f));
        *(us8*)p = o;
    }
}

// ---------------- SAGE layer, all 3 behaviors in one launch ----------------
// grid = 3*TILESN, b = blockIdx/TILESN. Computes pre-BN
//   h_out = mean_gather(h_in)@Wl + bl + h_in@Wr, accumulating BN stats.
// R2-measured-best config: 4 lanes/row x 32 cols, QUAD edge unroll, plain
// stores, (256,4) -> VGPR 56, zero spill, 227us. (R8's BN-fold spilled:
// compiler rounds VGPR down to wave boundaries and spills the excess.)
// Layer-1 outputs for b=1,2 go to d_out in 32-ROW TILE-BLOCK layout: attn
// tile tt owns u16 bytes [tt*16384, +16384); last tile -> ws tail buffer.

__global__ __launch_bounds__(256, 4) void sage_layer(
    const u16* __restrict__ hin0, const u16* __restrict__ wt_Wl,
    const u16* __restrict__ wt_Wr, const float* __restrict__ sage_bl,
    float* __restrict__ stats6, Out3 outs, int layer,
    const int* __restrict__ adj, const int* __restrict__ row_start,
    const int* __restrict__ cnt) {
    __shared__ u16 T1[64][136];
    __shared__ float sstat[256];
    const int tid = threadIdx.x;
    const int b = blockIdx.x / TILESN;
    const int tile = blockIdx.x % TILESN;
    const int r0 = tile * 64;
    const int bl = b * NL + layer;
    const u16* hin = hin0 + (layer ? (size_t)b * NNODE * DIM : 0);
    const u16* Wl = wt_Wl + (size_t)bl * 16384;
    const u16* Wr = wt_Wr + (size_t)bl * 16384;

    sstat[tid] = 0.f;

    // stage T1: mean-gather, 4 lanes x 32 cols per row, quad edge unroll
    {
        const int row = tid >> 2;
        const int c0 = (tid & 3) * 32;
        float a[32];
#pragma unroll
        for (int j = 0; j < 32; ++j) a[j] = 0.f;
        const int n = r0 + row;
        if (n < NNODE) {
            const int base = b * NNODE + n;
            const int s0 = row_start[base];
            const int deg = cnt[base];
            int e = 0;
            for (; e + 3 < deg; e += 4) {
                const int i0 = adj[s0 + e],     i1 = adj[s0 + e + 1];
                const int i2 = adj[s0 + e + 2], i3 = adj[s0 + e + 3];
                const u16* p0 = hin + (size_t)i0 * DIM + c0;
                const u16* p1 = hin + (size_t)i1 * DIM + c0;
                const u16* p2 = hin + (size_t)i2 * DIM + c0;
                const u16* p3 = hin + (size_t)i3 * DIM + c0;
                us8 u00 = *(const us8*)p0,        u01 = *(const us8*)(p0 + 8);
                us8 u02 = *(const us8*)(p0 + 16), u03 = *(const us8*)(p0 + 24);
                us8 u10 = *(const us8*)p1,        u11 = *(const us8*)(p1 + 8);
                us8 u12 = *(const us8*)(p1 + 16), u13 = *(const us8*)(p1 + 24);
                us8 u20 = *(const us8*)p2,        u21 = *(const us8*)(p2 + 8);
                us8 u22 = *(const us8*)(p2 + 16), u23 = *(const us8*)(p2 + 24);
                us8 u30 = *(const us8*)p3,        u31 = *(const us8*)(p3 + 8);
                us8 u32 = *(const us8*)(p3 + 16), u33 = *(const us8*)(p3 + 24);
#pragma unroll
                for (int j = 0; j < 8; ++j) {
                    a[j]      += (h2f(u00[j]) + h2f(u10[j])) + (h2f(u20[j]) + h2f(u30[j]));
                    a[8 + j]  += (h2f(u01[j]) + h2f(u11[j])) + (h2f(u21[j]) + h2f(u31[j]));
                    a[16 + j] += (h2f(u02[j]) + h2f(u12[j])) + (h2f(u22[j]) + h2f(u32[j]));
                    a[24 + j] += (h2f(u03[j]) + h2f(u13[j])) + (h2f(u23[j]) + h2f(u33[j]));
                }
            }
            if (e + 1 < deg) {
                const u16* p1 = hin + (size_t)adj[s0 + e] * DIM + c0;
                const u16* p2 = hin + (size_t)adj[s0 + e + 1] * DIM + c0;
                us8 u0 = *(const us8*)p1,        u1 = *(const us8*)(p1 + 8);
                us8 u2 = *(const us8*)(p1 + 16), u3 = *(const us8*)(p1 + 24);
                us8 v0 = *(const us8*)p2,        v1 = *(const us8*)(p2 + 8);
                us8 v2 = *(const us8*)(p2 + 16), v3 = *(const us8*)(p2 + 24);
#pragma unroll
                for (int j = 0; j < 8; ++j) {
                    a[j]      += h2f(u0[j]) + h2f(v0[j]);
                    a[8 + j]  += h2f(u1[j]) + h2f(v1[j]);
                    a[16 + j] += h2f(u2[j]) + h2f(v2[j]);
                    a[24 + j] += h2f(u3[j]) + h2f(v3[j]);
                }
                e += 2;
            }
            if (e < deg) {
                const u16* p1 = hin + (size_t)adj[s0 + e] * DIM + c0;
                us8 u0 = *(const us8*)p1,        u1 = *(const us8*)(p1 + 8);
                us8 u2 = *(const us8*)(p1 + 16), u3 = *(const us8*)(p1 + 24);
#pragma unroll
                for (int j = 0; j < 8; ++j) {
                    a[j]      += h2f(u0[j]);
                    a[8 + j]  += h2f(u1[j]);
                    a[16 + j] += h2f(u2[j]);
                    a[24 + j] += h2f(u3[j]);
                }
            }
            const float s = 1.0f / (float)(deg > 1 ? deg : 1);
#pragma unroll
            for (int j = 0; j < 32; ++j) a[j] *= s;
        }
#pragma unroll
        for (int k = 0; k < 4; ++k) {
            us8 o;
#pragma unroll
            for (int j = 0; j < 8; ++j) o[j] = f2h(a[8 * k + j]);
            *(us8*)&T1[row][c0 + 8 * k] = o;
        }
    }
    __syncthreads();

    // dual MFMA GEMM: A1 from LDS, A2 direct from global (LLC-hot)
    const int wave = tid >> 6, lane = tid & 63, q = lane >> 4, rlo = lane & 15;
    const f16x8 zf = (f16x8)(f16)0.f;
    f32x4 acc[4][2];
#pragma unroll
    for (int t = 0; t < 4; ++t) { acc[t][0] = (f32x4)0.f; acc[t][1] = (f32x4)0.f; }
#pragma unroll
    for (int kc = 0; kc < DIM; kc += 32) {
        f16x8 b1v[2], b2v[2];
#pragma unroll
        for (int c = 0; c < 2; ++c) {
            b1v[c] = *(const f16x8*)(Wl + (size_t)(wave * 32 + 16 * c + rlo) * DIM + kc + q * 8);
            b2v[c] = *(const f16x8*)(Wr + (size_t)(wave * 32 + 16 * c + rlo) * DIM + kc + q * 8);
        }
#pragma unroll
        for (int t = 0; t < 4; ++t) {
            f16x8 a1 = *(const f16x8*)&T1[16 * t + rlo][kc + q * 8];
            int rr = r0 + 16 * t + rlo;
            f16x8 a2 = (rr < NNODE) ? *(const f16x8*)(hin + (size_t)rr * DIM + kc + q * 8) : zf;
            acc[t][0] = __builtin_amdgcn_mfma_f32_16x16x32_f16(a1, b1v[0], acc[t][0], 0, 0, 0);
            acc[t][1] = __builtin_amdgcn_mfma_f32_16x16x32_f16(a1, b1v[1], acc[t][1], 0, 0, 0);
            acc[t][0] = __builtin_amdgcn_mfma_f32_16x16x32_f16(a2, b2v[0], acc[t][0], 0, 0, 0);
            acc[t][1] = __builtin_amdgcn_mfma_f32_16x16x32_f16(a2, b2v[1], acc[t][1], 0, 0, 0);
        }
    }

    const int col0 = wave * 32 + rlo, col1 = col0 + 16;
    const float bb0 = sage_bl[bl * DIM + col0], bb1 = sage_bl[bl * DIM + col1];
    const bool tiled = (layer == 1) && (b > 0);
    float rs0 = 0, rq0 = 0, rs1 = 0, rq1 = 0;
#pragma unroll
    for (int t = 0; t < 4; ++t) {
#pragma unroll
        for (int r = 0; r < 4; ++r) {
            int rloc = 16 * t + q * 4 + r;
            int row = r0 + rloc;
            if (row >= NNODE) continue;
            float v0 = acc[t][0][r] + bb0;
            float v1 = acc[t][1][r] + bb1;
            rs0 += v0; rq0 += v0 * v0; rs1 += v1; rq1 += v1 * v1;
            if (!tiled) {
                u16* C = outs.p[b];
                C[(size_t)row * DIM + col0] = f2h(v0);
                C[(size_t)row * DIM + col1] = f2h(v1);
            } else {
                int tt = row >> 5, rl = row & 31;
                u16* base = (tt == NT32 - 1) ? outs.p[2]
                                             : outs.p[1] + (size_t)tt * 8192;
                base += (size_t)(b - 1) * 4096 + rl * DIM;
                base[col0] = f2h(v0);
                base[col1] = f2h(v1);
            }
        }
    }
    rs0 += __shfl_xor(rs0, 16); rs0 += __shfl_xor(rs0, 32);
    rq0 += __shfl_xor(rq0, 16); rq0 += __shfl_xor(rq0, 32);
    rs1 += __shfl_xor(rs1, 16); rs1 += __shfl_xor(rs1, 32);
    rq1 += __shfl_xor(rq1, 16); rq1 += __shfl_xor(rq1, 32);
    if (q == 0) {
        atomicAdd(&sstat[col0], rs0);
        atomicAdd(&sstat[DIM + col0], rq0);
        atomicAdd(&sstat[col1], rs1);
        atomicAdd(&sstat[DIM + col1], rq1);
    }
    __syncthreads();
    if (tid < DIM) {
        float* so = stats6 + bl * 256;
        atomicAdd(&so[tid], sstat[tid]);
        atomicAdd(&so[DIM + tid], sstat[DIM + tid]);
    }
}

// ---------------- fused epilogue: BN+residual, Q/K logits, softmax, fuse, refine ----------------
// One block per 32-row tile (LDS ~30KB -> 5 blocks/CU). Reads h_pre (b0 linear
// from fbuf; b1,2 from its own 16KB tile block in d_out / tail) + xh; writes
// the final f32 output over exactly that byte range.

__global__ __launch_bounds__(256) void attn_fuse(
    const u16* __restrict__ hpre0, const u16* __restrict__ hpre12,
    const u16* __restrict__ tailb, const float* __restrict__ stats6,
    const float* __restrict__ gamma, const float* __restrict__ beta,
    const u16* __restrict__ xh, const u16* __restrict__ wt,
    const float* __restrict__ query_b, const float* __restrict__ key_b,
    const float* __restrict__ fuse_b, const float* __restrict__ refine_b,
    float* __restrict__ out) {
    __shared__ __attribute__((aligned(16))) u16 St[3][32][136];
    __shared__ float sc[3][DIM], sf[3][DIM];
    __shared__ float slog[32][4];
    __shared__ float swt[32][4];
    const int tid = threadIdx.x;
    const int tile = blockIdx.x;
    const int r0 = tile * 32;
    const u16* wt_q    = wt + 14 * 16384;
    const u16* wt_key  = wt + 15 * 16384;
    const u16* wt_fuse = wt + 18 * 16384;
    const u16* wt_ref  = wt + 19 * 16384;

    if (tid < DIM) {
        const float invN = 1.0f / (float)NNODE;
#pragma unroll
        for (int b = 0; b < NB; ++b) {
            const int bl = b * NL + 1;
            const float* st = stats6 + bl * 256;
            float mu = st[tid] * invN;
            float var = fmaxf(st[DIM + tid] * invN - mu * mu, 0.f);
            float c = gamma[bl * DIM + tid] * rsqrtf(var + BN_EPS);
            sc[b][tid] = c;
            sf[b][tid] = beta[bl * DIM + tid] - mu * c;
        }
    }
    if (tid < 32) { slog[tid][0] = 0.f; slog[tid][1] = 0.f; slog[tid][2] = 0.f; }
    __syncthreads();

    // stage stack tiles: St[b] = bn(h_pre) + xh
    for (int i = tid; i < 512; i += 256) {
        int r = i >> 4, c8 = (i & 15) * 8;
        int n = r0 + r;
        if (n < NNODE) {
            us8 xv = *(const us8*)(xh + (size_t)n * DIM + c8);
#pragma unroll
            for (int b = 0; b < NB; ++b) {
                const u16* src = (b == 0)
                    ? hpre0 + (size_t)n * DIM + c8
                    : ((tile == NT32 - 1) ? tailb : hpre12 + (size_t)tile * 8192)
                      + (size_t)(b - 1) * 4096 + r * DIM + c8;
                us8 hv = __builtin_nontemporal_load((const us8*)src);
                us8 o;
#pragma unroll
                for (int j = 0; j < 8; ++j)
                    o[j] = f2h(h2f(hv[j]) * sc[b][c8 + j] + sf[b][c8 + j] + h2f(xv[j]));
                *(us8*)&St[b][r][c8] = o;
            }
        } else {
            us8 z = (us8)(u16)0;
#pragma unroll
            for (int b = 0; b < NB; ++b) *(us8*)&St[b][r][c8] = z;
        }
    }
    __syncthreads();

    const int wave = tid >> 6, lane = tid & 63, q = lane >> 4, rlo = lane & 15;
    const int col0 = wave * 32 + rlo, col1 = col0 + 16;
    const f16x8 zf = (f16x8)(f16)0.f;

    // Q GEMM: A = xh (global), B = wt_q
    f32x4 qa[2][2];
#pragma unroll
    for (int t = 0; t < 2; ++t) { qa[t][0] = (f32x4)0.f; qa[t][1] = (f32x4)0.f; }
#pragma unroll
    for (int kc = 0; kc < DIM; kc += 32) {
        f16x8 bv0 = *(const f16x8*)(wt_q + (size_t)(wave * 32 + rlo) * DIM + kc + q * 8);
        f16x8 bv1 = *(const f16x8*)(wt_q + (size_t)(wave * 32 + 16 + rlo) * DIM + kc + q * 8);
#pragma unroll
        for (int t = 0; t < 2; ++t) {
            int rr = r0 + 16 * t + rlo;
            f16x8 av = (rr < NNODE) ? *(const f16x8*)(xh + (size_t)rr * DIM + kc + q * 8) : zf;
            qa[t][0] = __builtin_amdgcn_mfma_f32_16x16x32_f16(av, bv0, qa[t][0], 0, 0, 0);
            qa[t][1] = __builtin_amdgcn_mfma_f32_16x16x32_f16(av, bv1, qa[t][1], 0, 0, 0);
        }
    }
    {
        const float qb0 = query_b[col0], qb1 = query_b[col1];
#pragma unroll
        for (int t = 0; t < 2; ++t)
#pragma unroll
            for (int r = 0; r < 4; ++r) { qa[t][0][r] += qb0; qa[t][1][r] += qb1; }
    }

    // K GEMMs + logits into LDS
#pragma unroll
    for (int b = 0; b < NB; ++b) {
        f32x4 ka[2][2];
#pragma unroll
        for (int t = 0; t < 2; ++t) { ka[t][0] = (f32x4)0.f; ka[t][1] = (f32x4)0.f; }
        const u16* Wk = wt_key + (size_t)b * 16384;
#pragma unroll
        for (int kc = 0; kc < DIM; kc += 32) {
            f16x8 bv0 = *(const f16x8*)(Wk + (size_t)(wave * 32 + rlo) * DIM + kc + q * 8);
            f16x8 bv1 = *(const f16x8*)(Wk + (size_t)(wave * 32 + 16 + rlo) * DIM + kc + q * 8);
#pragma unroll
            for (int t = 0; t < 2; ++t) {
                f16x8 av = *(const f16x8*)&St[b][16 * t + rlo][kc + q * 8];
                ka[t][0] = __builtin_amdgcn_mfma_f32_16x16x32_f16(av, bv0, ka[t][0], 0, 0, 0);
                ka[t][1] = __builtin_amdgcn_mfma_f32_16x16x32_f16(av, bv1, ka[t][1], 0, 0, 0);
            }
        }
        const float kb0 = key_b[b * DIM + col0], kb1 = key_b[b * DIM + col1];
#pragma unroll
        for (int t = 0; t < 2; ++t) {
#pragma unroll
            for (int r = 0; r < 4; ++r) {
                int rloc = 16 * t + q * 4 + r;
                float v = (ka[t][0][r] + kb0) * qa[t][0][r]
                        + (ka[t][1][r] + kb1) * qa[t][1][r];
                v += __shfl_xor(v, 1);
                v += __shfl_xor(v, 2);
                v += __shfl_xor(v, 4);
                v += __shfl_xor(v, 8);
                if (rlo == 0) atomicAdd(&slog[rloc][b], v);
            }
        }
    }
    __syncthreads();

    if (tid < 32) {
        float l0 = slog[tid][0], l1 = slog[tid][1], l2 = slog[tid][2];
        float mm = fmaxf(l0, fmaxf(l1, l2));
        float e0 = expf(l0 - mm), e1 = expf(l1 - mm), e2 = expf(l2 - mm);
        float inv = 1.0f / (e0 + e1 + e2);
        swt[tid][0] = e0 * inv; swt[tid][1] = e1 * inv; swt[tid][2] = e2 * inv;
    }
    __syncthreads();

    // fuse GEMM: facc = sum_b w_b * (St_b @ Wf)
    f32x4 facc[2][2];
#pragma unroll
    for (int t = 0; t < 2; ++t) { facc[t][0] = (f32x4)0.f; facc[t][1] = (f32x4)0.f; }
#pragma unroll
    for (int b = 0; b < NB; ++b) {
        f32x4 ga[2][2];
#pragma unroll
        for (int t = 0; t < 2; ++t) { ga[t][0] = (f32x4)0.f; ga[t][1] = (f32x4)0.f; }
#pragma unroll
        for (int kc = 0; kc < DIM; kc += 32) {
            f16x8 bv0 = *(const f16x8*)(wt_fuse + (size_t)(wave * 32 + rlo) * DIM + kc + q * 8);
            f16x8 bv1 = *(const f16x8*)(wt_fuse + (size_t)(wave * 32 + 16 + rlo) * DIM + kc + q * 8);
#pragma unroll
            for (int t = 0; t < 2; ++t) {
                f16x8 av = *(const f16x8*)&St[b][16 * t + rlo][kc + q * 8];
                ga[t][0] = __builtin_amdgcn_mfma_f32_16x16x32_f16(av, bv0, ga[t][0], 0, 0, 0);
                ga[t][1] = __builtin_amdgcn_mfma_f32_16x16x32_f16(av, bv1, ga[t][1], 0, 0, 0);
            }
        }
#pragma unroll
        for (int t = 0; t < 2; ++t) {
#pragma unroll
            for (int r = 0; r < 4; ++r) {
                int rloc = 16 * t + q * 4 + r;
                float wgt = swt[rloc][b];
                facc[t][0][r] += wgt * ga[t][0][r];
                facc[t][1][r] += wgt * ga[t][1][r];
            }
        }
    }
    __syncthreads();   // all St reads done before Rt overwrite

    // round fused to f16 into St[0] (Rt) for the refine GEMM
    {
        const float fb0 = fuse_b[col0], fb1 = fuse_b[col1];
#pragma unroll
        for (int t = 0; t < 2; ++t) {
#pragma unroll
            for (int r = 0; r < 4; ++r) {
                int rloc = 16 * t + q * 4 + r;
                St[0][rloc][col0] = f2h(facc[t][0][r] + fb0);
                St[0][rloc][col1] = f2h(facc[t][1][r] + fb1);
            }
        }
    }
    __syncthreads();

    // refine GEMM + ReLU -> f32 out (overwrites this tile's d_out block)
    f32x4 racc[2][2];
#pragma unroll
    for (int t = 0; t < 2; ++t) { racc[t][0] = (f32x4)0.f; racc[t][1] = (f32x4)0.f; }
#pragma unroll
    for (int kc = 0; kc < DIM; kc += 32) {
        f16x8 bv0 = *(const f16x8*)(wt_ref + (size_t)(wave * 32 + rlo) * DIM + kc + q * 8);
        f16x8 bv1 = *(const f16x8*)(wt_ref + (size_t)(wave * 32 + 16 + rlo) * DIM + kc + q * 8);
#pragma unroll
        for (int t = 0; t < 2; ++t) {
            f16x8 av = *(const f16x8*)&St[0][16 * t + rlo][kc + q * 8];
            racc[t][0] = __builtin_amdgcn_mfma_f32_16x16x32_f16(av, bv0, racc[t][0], 0, 0, 0);
            racc[t][1] = __builtin_amdgcn_mfma_f32_16x16x32_f16(av, bv1, racc[t][1], 0, 0, 0);
        }
    }
    {
        const float rb0 = refine_b[col0], rb1 = refine_b[col1];
#pragma unroll
        for (int t = 0; t < 2; ++t) {
#pragma unroll
            for (int r = 0; r < 4; ++r) {
                int row = r0 + 16 * t + q * 4 + r;
                if (row >= NNODE) continue;
                __builtin_nontemporal_store(fmaxf(racc[t][0][r] + rb0, 0.f),
                                            &out[(size_t)row * DIM + col0]);
                __builtin_nontemporal_store(fmaxf(racc[t][1][r] + rb1, 0.f),
                                            &out[(size_t)row * DIM + col1]);
            }
        }
    }
}

// ---------------- plain MFMA GEMM (fp16 weights), 64x128 tile ----------------
// flags: 1=relu, 8=A f32, 32=C f16 (else f32)

__global__ __launch_bounds__(256) void gemm_p(
    const void* __restrict__ Av, const u16* __restrict__ Wt,
    const float* __restrict__ bias, void* __restrict__ Cv, int M, int flags) {
    const u16* A16 = (const u16*)Av;
    const float* A32 = (const float*)Av;
    const float* bs = bias;
    const int r0 = blockIdx.x * 64;
    const int tid = threadIdx.x;
    const int wave = tid >> 6, lane = tid & 63, q = lane >> 4, rlo = lane & 15;
    f32x4 acc[4][2];
#pragma unroll
    for (int t = 0; t < 4; ++t) { acc[t][0] = (f32x4)0.f; acc[t][1] = (f32x4)0.f; }
    const f16x8 zf = (f16x8)(f16)0.f;
#pragma unroll
    for (int kc = 0; kc < DIM; kc += 32) {
        f16x8 av[4], bv[2];
#pragma unroll
        for (int t = 0; t < 4; ++t) {
            int row = r0 + 16 * t + rlo;
            if (row < M) {
                if (flags & 8) {
                    const float* p = A32 + (size_t)row * DIM + kc + q * 8;
                    f32x4 x0 = __builtin_nontemporal_load((const f32x4*)p);
                    f32x4 x1 = __builtin_nontemporal_load((const f32x4*)(p + 4));
                    f16x8 tmp;
                    tmp[0] = (f16)x0[0]; tmp[1] = (f16)x0[1]; tmp[2] = (f16)x0[2]; tmp[3] = (f16)x0[3];
                    tmp[4] = (f16)x1[0]; tmp[5] = (f16)x1[1]; tmp[6] = (f16)x1[2]; tmp[7] = (f16)x1[3];
                    av[t] = tmp;
                } else {
                    av[t] = *(const f16x8*)(A16 + (size_t)row * DIM + kc + q * 8);
                }
            } else {
                av[t] = zf;
            }
        }
#pragma unroll
        for (int c = 0; c < 2; ++c)
            bv[c] = *(const f16x8*)(Wt + (size_t)(wave * 32 + 16 * c + rlo) * DIM + kc + q * 8);
#pragma unroll
        for (int t = 0; t < 4; ++t) {
            acc[t][0] = __builtin_amdgcn_mfma_f32_16x16x32_f16(av[t], bv[0], acc[t][0], 0, 0, 0);
            acc[t][1] = __builtin_amdgcn_mfma_f32_16x16x32_f16(av[t], bv[1], acc[t][1], 0, 0, 0);
        }
    }

    const int col0 = wave * 32 + rlo, col1 = col0 + 16;
    const float bb0 = bs[col0], bb1 = bs[col1];
#pragma unroll
    for (int t = 0; t < 4; ++t) {
#pragma unroll
        for (int r = 0; r < 4; ++r) {
            int row = r0 + 16 * t + q * 4 + r;
            if (row >= M) continue;
            float v0 = acc[t][0][r] + bb0;
            float v1 = acc[t][1][r] + bb1;
            if (flags & 1) { v0 = fmaxf(v0, 0.f); v1 = fmaxf(v1, 0.f); }
            if (flags & 32) {
                ((u16*)Cv)[(size_t)row * DIM + col0] = f2h(v0);
                ((u16*)Cv)[(size_t)row * DIM + col1] = f2h(v1);
            } else {
                ((float*)Cv)[(size_t)row * DIM + col0] = v0;
                ((float*)Cv)[(size_t)row * DIM + col1] = v1;
            }
        }
    }
}

// ---------------- launch ----------------

extern "C" void kernel_launch(void* const* d_in, const int* in_sizes, int n_in,
                              void* d_out, int out_size, void* d_ws, size_t ws_size,
                              hipStream_t stream) {
    const int* edge_index    = (const int*)d_in[0];
    const int* edge_type     = (const int*)d_in[1];
    const float* item_feats  = (const float*)d_in[2];
    const float* user_emb    = (const float*)d_in[3];
    const float* user_proj_b = (const float*)d_in[5];
    const float* item_proj_b = (const float*)d_in[7];
    const float* sage_bl  = (const float*)d_in[9];
    const float* bn_gamma = (const float*)d_in[11];
    const float* bn_beta  = (const float*)d_in[12];
    const float* query_b  = (const float*)d_in[14];
    const float* key_b    = (const float*)d_in[16];
    const float* fuse_b   = (const float*)d_in[18];
    const float* refine_b = (const float*)d_in[20];
    const int E = in_sizes[1];

    const size_t ND = (size_t)NNODE * DIM;
    char* w = (char*)d_ws;
    u16* xh = (u16*)w;          w += ND * 2;              // initial x, fp16
    u16* stackb = (u16*)w;      w += NB * ND * 2;         // pre-BN l0 h -> activated l0
    u16* fbuf = (u16*)w;        w += ND * 2;              // h_pre layer1 slice 0
    int* cnt = (int*)w;         w += (size_t)NT3P * 4;
    int* row_start = (int*)w;   w += (size_t)NT3P * 4;
    int* cur = (int*)w;         w += (size_t)NT3P * 4;
    int* adj = (int*)w;         w += (size_t)E * 4;
    u16* wt = (u16*)w;          w += (size_t)20 * 16384 * 2;
    int* bsum = (int*)w;        w += 2048;
    float* stats6 = (float*)w;  w += 6 * 256 * 4;
    u16* tailb = (u16*)w;       w += 16384;               // last-tile h_pre slices 1,2

    const u16* wt_user = wt;
    const u16* wt_item = wt + 16384;
    const u16* wt_Wl   = wt + 2 * 16384;
    const u16* wt_Wr   = wt + 8 * 16384;

    u16* dout16 = (u16*)d_out;   // during SAGE L1: 32-row tiled h_pre slices 1,2; then final f32 out

    // ---- CSR build + weight conversion ----
    hipMemsetAsync(cnt, 0, (size_t)NT3P * 4, stream);
    hipMemsetAsync(stats6, 0, 6 * 256 * 4, stream);
    int gE = (E + 255) / 256;
    count_edges<<<gE, 256, 0, stream>>>(edge_index, edge_type, E, cnt);
    scan1<<<SCAN_BLOCKS, 256, 0, stream>>>(cnt, bsum);
    scan2<<<1, 512, 0, stream>>>(bsum, SCAN_BLOCKS);
    scan3<<<SCAN_BLOCKS, 256, 0, stream>>>(cnt, bsum, row_start, cur);
    scatter_csr<<<gE, 256, 0, stream>>>(edge_index, edge_type, E, cur, adj);

    WPtrs wp;
    wp.s[0] = (const float*)d_in[4];
    wp.s[1] = (const float*)d_in[6];
    wp.s[2] = (const float*)d_in[8];
    wp.s[3] = (const float*)d_in[10];
    wp.s[4] = (const float*)d_in[13];
    wp.s[5] = (const float*)d_in[15];
    wp.s[6] = (const float*)d_in[17];
    wp.s[7] = (const float*)d_in[19];
    wconv_all<<<1280, 256, 0, stream>>>(wp, wt);

    // ---- initial projection (f32 in, fp16 out) ----
    const int TU = (NUSER + 63) / 64, TI = (NITEM + 63) / 64;
    gemm_p<<<TU, 256, 0, stream>>>(user_emb, wt_user, user_proj_b, xh, NUSER, 8 | 32);
    gemm_p<<<TI, 256, 0, stream>>>(item_feats, wt_item, item_proj_b,
                                   xh + (size_t)NUSER * DIM, NITEM, 8 | 32);

    // ---- SAGE: layer0 -> activate in place (grid-stride stream) -> layer1 ----
    Out3 out_l0, out_l1;
    for (int b = 0; b < NB; ++b) out_l0.p[b] = stackb + (size_t)b * ND;
    out_l1.p[0] = fbuf;
    out_l1.p[1] = dout16;   // 32-row tiled layout
    out_l1.p[2] = tailb;    // last 32-row tile

    sage_layer<<<NB * TILESN, 256, 0, stream>>>(xh, wt_Wl, wt_Wr, sage_bl,
                                                stats6, out_l0, 0,
                                                adj, row_start, cnt);
    bn_apply<<<NB * BNBLKS, 256, 0, stream>>>(stackb, stats6, bn_gamma, bn_beta);
    sage_layer<<<NB * TILESN, 256, 0, stream>>>(stackb, wt_Wl, wt_Wr, sage_bl,
                                                stats6, out_l1, 1,
                                                adj, row_start, cnt);

    // ---- fused attention epilogue: BN+residual, logits, softmax, fuse, refine ----
    attn_fuse<<<NT32, 256, 0, stream>>>(fbuf, dout16, tailb, stats6,
                                        bn_gamma, bn_beta, xh, wt,
                                        query_b, key_b, fuse_b, refine_b,
                                        (float*)d_out);
}